// Round 3
// baseline (80.069 us; speedup 1.0000x reference)
//
#include <hip/hip_runtime.h>
#include <math.h>

// Problem constants (hardcoded in reference)
#define V 2048
#define DF 128
#define NK 73          // 1 + J + J^2 branch outputs
#define RPB 8          // rows (graph nodes) per block
#define NB (V / RPB)   // 256 blocks
#define A_F 0.34657359027997264f   // A = R*ln(2)/(J-R+1) = ln2/2
#define TWO_PI_F 6.283185307179586f

// d_out is poisoned 0xAA before every timed call; zero it (stream-ordered
// before k_fused, which accumulates into it with atomics).
__global__ __launch_bounds__(256) void k_zero(float* __restrict__ out) {
    int i = blockIdx.x * 256 + threadIdx.x;
    if (i < NK * DF) out[i] = 0.0f;
}

// Fully fused scattering. Block b owns rows v0..v0+7 of W. The reference's
// Lmat = diag(deg)*dhalf*dhalf^T is EXACTLY diagonal, so eigh is a signed
// permutation and every filter matrix g_j is diag(h_j(deg[v])) -> the whole
// 2-layer scattering is pointwise in v, and block b only needs ITS OWN rows'
// degrees. No inter-block dependency.
__global__ __launch_bounds__(256) void k_fused(const float* __restrict__ W,
                                               const float* __restrict__ f,
                                               float* __restrict__ out) {
    __shared__ float degs[RPB];
    __shared__ float cl[8][RPB];          // [filter j][local v]
    __shared__ float red[NK * DF];        // 37 KB: rep-1 partials
    const int tid  = threadIdx.x;
    const int wave = tid >> 6, lane = tid & 63;
    const int v0   = blockIdx.x * RPB;

    // ---- Phase A: rowsums. Each wave sums 2 rows (row = 512 float4). ----
    #pragma unroll
    for (int rr = 0; rr < 2; ++rr) {
        const int vloc = wave * 2 + rr;
        const float4* row = (const float4*)(W + (size_t)(v0 + vloc) * V);
        float s = 0.0f;
        #pragma unroll
        for (int k = 0; k < 8; ++k) {
            float4 a = row[lane + 64 * k];
            s += (a.x + a.y) + (a.z + a.w);
        }
        #pragma unroll
        for (int off = 32; off > 0; off >>= 1) s += __shfl_xor(s, off, 64);
        if (lane == 0) degs[vloc] = s;
    }
    __syncthreads();

    // ---- Phase B: filter responses at E = deg/max(1,deg), threads 0..7. ----
    if (tid < RPB) {
        float deg = degs[tid];
        float e = fabsf(deg / fmaxf(1.0f, deg));
        float x = logf(e);
        float sumsq = 0.0f, wv[7];
        #pragma unroll
        for (int j = 2; j <= 8; ++j) {
            float t = x - A_F * (float)(j - 1) * (1.0f / 3.0f);  // R = 3
            float val = 0.0f;
            if (t > -A_F && t <= 0.0f)
                val = 0.5f + 0.5f * cosf(TWO_PI_F * (t / A_F + 0.5f));
            wv[j - 2] = val;
            sumsq += val * val;
        }
        // (R/2)(d0^2+d1^2) + (R/2)d0^2 - sum wav^2 = 1.125 - sumsq
        cl[0][tid] = sqrtf(fmaxf(1.125f - sumsq, 0.0f));   // scaling
        #pragma unroll
        for (int j = 0; j < 7; ++j) cl[j + 1][tid] = wv[j];
    }
    __syncthreads();

    // ---- Phase C: 73 branch partial sums. rep 0 -> v 0..3, rep 1 -> 4..7. ----
    const int rep = tid >> 7;      // waves {0,1}=rep0, {2,3}=rep1
    const int d   = tid & 127;
    float acc[NK];
    #pragma unroll
    for (int k = 0; k < NK; ++k) acc[k] = 0.0f;
    #pragma unroll
    for (int i = 0; i < 4; ++i) {
        const int vloc = rep * 4 + i;
        float fv = f[(size_t)(v0 + vloc) * DF + d];
        float af = fabsf(fv);
        float cj[8];
        #pragma unroll
        for (int j = 0; j < 8; ++j) cj[j] = cl[j][vloc];  // wave-uniform: LDS broadcast
        acc[0] += fv;                                     // layer-0 mean (no abs)
        float tu[8];
        #pragma unroll
        for (int u = 0; u < 8; ++u) { tu[u] = cj[u] * af; acc[1 + u] += tu[u]; }
        #pragma unroll
        for (int u = 0; u < 8; ++u)
            #pragma unroll
            for (int j = 0; j < 8; ++j)
                acc[9 + u * 8 + j] += tu[u] * cj[j];      // c_u*c_j*|f|
    }

    // ---- Phase D: rep-reduce in LDS, one atomicAdd stream from rep 0. ----
    if (rep == 1) {
        #pragma unroll
        for (int k = 0; k < NK; ++k) red[k * DF + d] = acc[k];
    }
    __syncthreads();
    if (rep == 0) {
        #pragma unroll
        for (int k = 0; k < NK; ++k)
            atomicAdd(&out[k * DF + d], (acc[k] + red[k * DF + d]) * (1.0f / (float)V));
    }
}

extern "C" void kernel_launch(void* const* d_in, const int* in_sizes, int n_in,
                              void* d_out, int out_size, void* d_ws, size_t ws_size,
                              hipStream_t stream) {
    const float* W = (const float*)d_in[0];   // fp32 [V,V]
    const float* f = (const float*)d_in[1];   // fp32 [V,DF]
    float* out = (float*)d_out;               // fp32 [NK*DF]

    k_zero<<<(NK * DF + 255) / 256, 256, 0, stream>>>(out);
    k_fused<<<NB, 256, 0, stream>>>(W, f, out);
}

// Round 4
// 78.704 us; speedup vs baseline: 1.0173x; 1.0173x over previous
//
#include <hip/hip_runtime.h>
#include <math.h>

// Problem constants (hardcoded in reference)
#define V 2048
#define DF 128
#define NK 73          // 1 + J + J^2 branch outputs
#define RPB 8          // rows (graph nodes) per block
#define NB (V / RPB)   // 256 blocks
#define A_F 0.34657359027997264f   // A = R*ln(2)/(J-R+1) = ln2/2
#define TWO_PI_F 6.283185307179586f

// Fully fused scattering, stage 1. Block b owns rows v0..v0+7 of W. The
// reference's Lmat = diag(deg)*dhalf*dhalf^T is EXACTLY diagonal, so eigh is
// a signed permutation and every filter matrix g_j is diag(h_j(deg[v])) ->
// the 2-layer scattering is pointwise in v and block b only needs ITS OWN
// rows' degrees. No inter-block dependency; partials written non-atomically
// (round 3's 256-way atomicAdd contention cost ~4-5 us — removed).
__global__ __launch_bounds__(256) void k_fused(const float* __restrict__ W,
                                               const float* __restrict__ f,
                                               float* __restrict__ part) {
    __shared__ float degs[RPB];
    __shared__ float cl[8][RPB];          // [filter j][local v]
    __shared__ float red[NK * DF];        // 37 KB: rep-1 partials
    const int tid  = threadIdx.x;
    const int wave = tid >> 6, lane = tid & 63;
    const int v0   = blockIdx.x * RPB;

    // ---- Phase A: rowsums. Each wave sums 2 rows (row = 512 float4). ----
    #pragma unroll
    for (int rr = 0; rr < 2; ++rr) {
        const int vloc = wave * 2 + rr;
        const float4* row = (const float4*)(W + (size_t)(v0 + vloc) * V);
        float s = 0.0f;
        #pragma unroll
        for (int k = 0; k < 8; ++k) {
            float4 a = row[lane + 64 * k];
            s += (a.x + a.y) + (a.z + a.w);
        }
        #pragma unroll
        for (int off = 32; off > 0; off >>= 1) s += __shfl_xor(s, off, 64);
        if (lane == 0) degs[vloc] = s;
    }
    __syncthreads();

    // ---- Phase B: filter responses at E = deg/max(1,deg), threads 0..7. ----
    if (tid < RPB) {
        float deg = degs[tid];
        float e = fabsf(deg / fmaxf(1.0f, deg));
        float x = logf(e);
        float sumsq = 0.0f, wv[7];
        #pragma unroll
        for (int j = 2; j <= 8; ++j) {
            float t = x - A_F * (float)(j - 1) * (1.0f / 3.0f);  // R = 3
            float val = 0.0f;
            if (t > -A_F && t <= 0.0f)
                val = 0.5f + 0.5f * cosf(TWO_PI_F * (t / A_F + 0.5f));
            wv[j - 2] = val;
            sumsq += val * val;
        }
        // (R/2)(d0^2+d1^2) + (R/2)d0^2 - sum wav^2 = 1.125 - sumsq
        cl[0][tid] = sqrtf(fmaxf(1.125f - sumsq, 0.0f));   // scaling
        #pragma unroll
        for (int j = 0; j < 7; ++j) cl[j + 1][tid] = wv[j];
    }
    __syncthreads();

    // ---- Phase C: 73 branch partials. rep 0 -> v 0..3, rep 1 -> 4..7. ----
    const int rep = tid >> 7;      // waves {0,1}=rep0, {2,3}=rep1
    const int d   = tid & 127;
    float acc[NK];
    #pragma unroll
    for (int k = 0; k < NK; ++k) acc[k] = 0.0f;
    #pragma unroll
    for (int i = 0; i < 4; ++i) {
        const int vloc = rep * 4 + i;
        float fv = f[(size_t)(v0 + vloc) * DF + d];
        float af = fabsf(fv);
        float cj[8];
        #pragma unroll
        for (int j = 0; j < 8; ++j) cj[j] = cl[j][vloc];  // wave-uniform: LDS broadcast
        acc[0] += fv;                                     // layer-0 mean (no abs)
        float tu[8];
        #pragma unroll
        for (int u = 0; u < 8; ++u) { tu[u] = cj[u] * af; acc[1 + u] += tu[u]; }
        #pragma unroll
        for (int u = 0; u < 8; ++u)
            #pragma unroll
            for (int j = 0; j < 8; ++j)
                acc[9 + u * 8 + j] += tu[u] * cj[j];      // c_u*c_j*|f|
    }

    // ---- Phase D: rep-reduce in LDS, coalesced non-atomic partial store. ----
    if (rep == 1) {
        #pragma unroll
        for (int k = 0; k < NK; ++k) red[k * DF + d] = acc[k];
    }
    __syncthreads();
    if (rep == 0) {
        float* p = part + (size_t)blockIdx.x * (NK * DF);
        #pragma unroll
        for (int k = 0; k < NK; ++k)
            p[k * DF + d] = acc[k] + red[k * DF + d];
    }
}

// Stage 2: sum the NB per-block partials, apply mean (1/V), write out.
// Reads are coalesced across threads for each b-iteration (stride NK*DF).
__global__ __launch_bounds__(256) void k_reduce(const float* __restrict__ part,
                                               float* __restrict__ out) {
    const int i = blockIdx.x * 256 + threadIdx.x;
    if (i < NK * DF) {
        float s = 0.0f;
        for (int b = 0; b < NB; ++b) s += part[(size_t)b * (NK * DF) + i];
        out[i] = s * (1.0f / (float)V);
    }
}

extern "C" void kernel_launch(void* const* d_in, const int* in_sizes, int n_in,
                              void* d_out, int out_size, void* d_ws, size_t ws_size,
                              hipStream_t stream) {
    const float* W = (const float*)d_in[0];   // fp32 [V,V]
    const float* f = (const float*)d_in[1];   // fp32 [V,DF]
    float* out = (float*)d_out;               // fp32 [NK*DF]
    float* part = (float*)d_ws;               // NB * NK * DF floats = 9.5 MB

    k_fused<<<NB, 256, 0, stream>>>(W, f, part);
    k_reduce<<<(NK * DF + 255) / 256, 256, 0, stream>>>(part, out);
}

// Round 5
// 76.610 us; speedup vs baseline: 1.0452x; 1.0273x over previous
//
#include <hip/hip_runtime.h>
#include <math.h>

// Problem constants (hardcoded in reference)
#define V 2048
#define DF 128
#define NK 73          // 1 + J + J^2 branch outputs
#define NSL 128        // v-slices in k_scatter (16 rows each)
#define A_F 0.34657359027997264f   // A = R*ln(2)/(J-R+1) = ln2/2
#define TWO_PI_F 6.283185307179586f

// Stage 1: one block per node v. deg[v] = rowsum(W), then the J=8 filter
// responses at E = deg/max(1,deg). The reference's Lmat = diag(deg)*dhalf^2
// is EXACTLY diagonal, so eigh is a signed permutation and every filter
// matrix g_j is diag(h_j(deg[v])) — the whole scattering is pointwise in v.
// 2048 blocks -> 8 blocks/CU: full latency hiding for the 16.8 MB W read.
__global__ __launch_bounds__(256) void k_filters(const float* __restrict__ W,
                                                 float* __restrict__ c) {
    __shared__ float red[4];
    const int v = blockIdx.x;
    const int tid = threadIdx.x;
    // row = 2048 fp32 = 512 float4; 256 threads * 2 float4 each, coalesced
    const float4* row = (const float4*)(W + (size_t)v * V);
    float4 a = row[tid];
    float4 b = row[tid + 256];
    float s = ((a.x + a.y) + (a.z + a.w)) + ((b.x + b.y) + (b.z + b.w));
    #pragma unroll
    for (int off = 32; off > 0; off >>= 1) s += __shfl_down(s, off, 64);
    if ((tid & 63) == 0) red[tid >> 6] = s;
    __syncthreads();
    if (tid == 0) {
        float deg = (red[0] + red[1]) + (red[2] + red[3]);
        float e = fabsf(deg / fmaxf(1.0f, deg));
        float x = logf(e);
        float sumsq = 0.0f, wv[7];
        #pragma unroll
        for (int j = 2; j <= 8; ++j) {
            float t = x - A_F * (float)(j - 1) * (1.0f / 3.0f);  // R = 3
            float val = 0.0f;
            if (t > -A_F && t <= 0.0f)
                val = 0.5f + 0.5f * cosf(TWO_PI_F * (t / A_F + 0.5f));
            wv[j - 2] = val;
            sumsq += val * val;
        }
        // (R/2)(d0^2+d1^2) + (R/2)d0^2 - sum wav^2 = 1.125 - sumsq
        c[v] = sqrtf(fmaxf(1.125f - sumsq, 0.0f));   // scaling (j index 0)
        #pragma unroll
        for (int j = 0; j < 7; ++j) c[(j + 1) * V + v] = wv[j];
    }
}

// Stage 2: slice-based scatter. Block = one 16-row v-slice; two replicas of
// 128 d-threads each take 8 rows, accumulate ALL 73 branches in VGPRs
// (f read once total, vs 73x in the branch-per-block layout), LDS-reduce the
// replicas, write one non-atomic partial per slice.
__global__ __launch_bounds__(256) void k_scatter(const float* __restrict__ f,
                                                 const float* __restrict__ c,
                                                 float* __restrict__ part) {
    __shared__ float red[NK * DF];        // 37 KB
    const int tid = threadIdx.x;
    const int rep = tid >> 7;             // 0 or 1
    const int d   = tid & 127;
    const int v0  = blockIdx.x * (V / NSL) + rep * 8;
    float acc[NK];
    #pragma unroll
    for (int k = 0; k < NK; ++k) acc[k] = 0.0f;
    #pragma unroll
    for (int i = 0; i < 8; ++i) {
        const int v = v0 + i;
        float fv = f[(size_t)v * DF + d];
        float af = fabsf(fv);
        float cj[8];
        #pragma unroll
        for (int j = 0; j < 8; ++j) cj[j] = c[j * V + v];  // uniform -> broadcast
        acc[0] += fv;                                      // layer-0 mean (no abs)
        float tu[8];
        #pragma unroll
        for (int u = 0; u < 8; ++u) { tu[u] = cj[u] * af; acc[1 + u] += tu[u]; }
        #pragma unroll
        for (int u = 0; u < 8; ++u)
            #pragma unroll
            for (int j = 0; j < 8; ++j)
                acc[9 + u * 8 + j] += tu[u] * cj[j];       // c_u*c_j*|f|
    }
    if (rep == 1) {
        #pragma unroll
        for (int k = 0; k < NK; ++k) red[k * DF + d] = acc[k];
    }
    __syncthreads();
    if (rep == 0) {
        float* p = part + (size_t)blockIdx.x * (NK * DF);
        #pragma unroll
        for (int k = 0; k < NK; ++k)
            p[k * DF + d] = acc[k] + red[k * DF + d];
    }
}

// Stage 3: one block per branch k; thread d sums the NSL partials (coalesced
// 512 B per step, L2-resident), applies mean (1/V).
__global__ __launch_bounds__(128) void k_reduce(const float* __restrict__ part,
                                                float* __restrict__ out) {
    const int k = blockIdx.x;
    const int d = threadIdx.x;
    float s = 0.0f;
    #pragma unroll 8
    for (int sl = 0; sl < NSL; ++sl)
        s += part[((size_t)sl * NK + k) * DF + d];
    out[k * DF + d] = s * (1.0f / (float)V);
}

extern "C" void kernel_launch(void* const* d_in, const int* in_sizes, int n_in,
                              void* d_out, int out_size, void* d_ws, size_t ws_size,
                              hipStream_t stream) {
    const float* W = (const float*)d_in[0];   // fp32 [V,V]
    const float* f = (const float*)d_in[1];   // fp32 [V,DF]
    float* out = (float*)d_out;               // fp32 [NK*DF]

    float* c    = (float*)d_ws;               // 8*V floats = 64 KB
    float* part = c + 8 * V;                  // NSL*NK*DF floats = 4.8 MB

    k_filters<<<V, 256, 0, stream>>>(W, c);
    k_scatter<<<NSL, 256, 0, stream>>>(f, c, part);
    k_reduce<<<NK, DF, 0, stream>>>(part, out);
}